// Round 3
// baseline (462.122 us; speedup 1.0000x reference)
//
#include <hip/hip_runtime.h>
#include <hip/hip_bf16.h>
#include <stdint.h>

// Problem constants (B,C,H,W)=(16,256,64,64), HEADS=8, BS=8, HALO=3
// Inputs are float32 (per reference setup_inputs); MFMA math in bf16,
// f32 accumulate; output f32.
#define HEADS 8
#define WIN 14
#define NPOS 196          // WIN*WIN
#define NPAD 224          // padded key count = 7*32
#define NB 16
#define NC 256
#define NH 64
#define NW 64
#define NP 4096           // NH*NW
#define NKV 512           // kv channels

typedef __bf16 bf16_t;
typedef bf16_t bf16x8 __attribute__((ext_vector_type(8)));
typedef float f32x4 __attribute__((ext_vector_type(4)));

union Frag {
  uint4 u4;
  bf16x8 b8;
  ushort us[8];
};

__device__ __forceinline__ ushort f2bf(float f) {
  bf16_t h = (bf16_t)f;
  return __builtin_bit_cast(ushort, h);
}

// load 8 consecutive f32, round to bf16x8 fragment
__device__ __forceinline__ bf16x8 load_bf8(const float* __restrict__ p) {
  float4 a = *reinterpret_cast<const float4*>(p);
  float4 b = *reinterpret_cast<const float4*>(p + 4);
  bf16x8 r;
  r[0] = (bf16_t)a.x; r[1] = (bf16_t)a.y; r[2] = (bf16_t)a.z; r[3] = (bf16_t)a.w;
  r[4] = (bf16_t)b.x; r[5] = (bf16_t)b.y; r[6] = (bf16_t)b.z; r[7] = (bf16_t)b.w;
  return r;
}

// ---------------------------------------------------------------------------
// K1: kv projection. kvb[b][p][oc] = sum_c x[b][c][p] * Wkv[oc][c]  (bf16 out)
// One wg = one image row (64 positions) x 128 oc. f32 x-tile transposed into
// LDS as bf16 during staging; fragment reads are aligned b128.
// ---------------------------------------------------------------------------
__global__ __launch_bounds__(256) void k_kv(const float* __restrict__ x,
                                            const float* __restrict__ wkv,
                                            ushort* __restrict__ kvb) {
  __shared__ __align__(16) ushort As[64][264];
  const int b = blockIdx.z;
  const int y = blockIdx.x;          // image row; p = y*64 + px
  const int n0 = blockIdx.y * 128;
  const int tid = threadIdx.x;
  const int lane = tid & 63, wid = tid >> 6;
  const int quad = lane >> 4, lc = lane & 15;
  // stage: As[px][c] <- bf16(x[b][c][y][px])
  #pragma unroll
  for (int it = 0; it < 16; ++it) {
    int i = it * 256 + tid;
    int c = i >> 4, xs = (i & 15) * 4;
    float4 v = *reinterpret_cast<const float4*>(x + ((size_t)(b * NC + c)) * NP + y * NW + xs);
    As[xs + 0][c] = f2bf(v.x);
    As[xs + 1][c] = f2bf(v.y);
    As[xs + 2][c] = f2bf(v.z);
    As[xs + 3][c] = f2bf(v.w);
  }
  __syncthreads();
  const int wm = (wid & 1) * 32, wn = (wid >> 1) * 64;
  f32x4 acc[2][4] = {};
  #pragma unroll
  for (int ks = 0; ks < 8; ++ks) {
    const int k0 = ks * 32 + quad * 8;
    Frag a[2];
    bf16x8 bb[4];
    #pragma unroll
    for (int mt = 0; mt < 2; ++mt)
      a[mt].u4 = *reinterpret_cast<const uint4*>(&As[wm + mt * 16 + lc][k0]);
    #pragma unroll
    for (int nt = 0; nt < 4; ++nt) {
      int oc = n0 + wn + nt * 16 + lc;
      bb[nt] = load_bf8(wkv + (size_t)oc * NC + k0);
    }
    #pragma unroll
    for (int mt = 0; mt < 2; ++mt)
      #pragma unroll
      for (int nt = 0; nt < 4; ++nt)
        acc[mt][nt] = __builtin_amdgcn_mfma_f32_16x16x32_bf16(a[mt].b8, bb[nt], acc[mt][nt], 0, 0, 0);
  }
  #pragma unroll
  for (int mt = 0; mt < 2; ++mt) {
    #pragma unroll
    for (int r = 0; r < 4; ++r) {
      int pl = wm + mt * 16 + quad * 4 + r;
      #pragma unroll
      for (int nt = 0; nt < 4; ++nt) {
        int oc = n0 + wn + nt * 16 + lc;
        kvb[((size_t)(b * NP + y * NW + pl)) * NKV + oc] = f2bf(acc[mt][nt][r]);
      }
    }
  }
}

// ---------------------------------------------------------------------------
// K2: halo attention with on-the-fly q projection.
// One wg per (b, block, head); 4 waves x 16 queries. Output f32.
// ---------------------------------------------------------------------------
__global__ __launch_bounds__(256) void k_attn(const float* __restrict__ x,
                                              const float* __restrict__ wq,
                                              const ushort* __restrict__ kvb,
                                              const float* __restrict__ pbias,
                                              float* __restrict__ out) {
  __shared__ __align__(16) ushort ksh[NPAD][40];     // [key][d]
  __shared__ __align__(16) ushort vth[32][232];      // [d][key]
  __shared__ __align__(16) ushort psh[4][16][232];   // per-wave P tiles
  __shared__ __align__(16) ushort qsh[4][16][32];    // per-wave q C->A round trip
  __shared__ __align__(16) float osh[64][33];
  const int b = blockIdx.z, h = blockIdx.y, blk = blockIdx.x;
  const int by = blk >> 3, bx = blk & 7;
  const int tid = threadIdx.x, lane = tid & 63, w = tid >> 6;
  const int quad = lane >> 4, lc = lane & 15;

  // stage KV window: 224 pos x 8 segs(8 bf16) ; segs 0..3 -> k, 4..7 -> v^T
  for (int it = 0; it < 7; ++it) {
    int i = it * 256 + tid;
    int pos = i >> 3, seg = i & 7;
    Frag v;
    v.u4 = make_uint4(0u, 0u, 0u, 0u);
    if (pos < NPOS) {
      int wy = pos / WIN;
      int wx = pos - wy * WIN;
      int yq = by * 8 - 3 + wy, xx = bx * 8 - 3 + wx;
      if ((unsigned)yq < (unsigned)NH && (unsigned)xx < (unsigned)NW)
        v.u4 = *reinterpret_cast<const uint4*>(
            kvb + ((size_t)(b * NP + yq * NW + xx)) * NKV + h * 64 + seg * 8);
    }
    if (seg < 4) {
      *reinterpret_cast<uint4*>(&ksh[pos][seg * 8]) = v.u4;
    } else {
      int d0 = (seg - 4) * 8;
      #pragma unroll
      for (int j = 0; j < 8; ++j) vth[d0 + j][pos] = v.us[j];
    }
  }

  // on-the-fly q projection: q[m=w*16+lc][d] = sum_c x[c][p(m)] * Wq[h*32+d][c]
  f32x4 qacc[2] = {};
  {
    const int q = w * 16 + lc;
    const size_t p = (size_t)(by * 8 + (q >> 3)) * NW + bx * 8 + (q & 7);
    #pragma unroll
    for (int ks = 0; ks < 8; ++ks) {
      const int k0 = ks * 32 + quad * 8;
      Frag ax;
      #pragma unroll
      for (int j = 0; j < 8; ++j)
        ax.us[j] = f2bf(x[((size_t)(b * NC + k0 + j)) * NP + p]);
      bf16x8 bw0 = load_bf8(wq + (size_t)(h * 32 + lc) * NC + k0);
      bf16x8 bw1 = load_bf8(wq + (size_t)(h * 32 + 16 + lc) * NC + k0);
      qacc[0] = __builtin_amdgcn_mfma_f32_16x16x32_bf16(ax.b8, bw0, qacc[0], 0, 0, 0);
      qacc[1] = __builtin_amdgcn_mfma_f32_16x16x32_bf16(ax.b8, bw1, qacc[1], 0, 0, 0);
    }
  }
  // q C-layout -> A-layout round trip (per-wave LDS region)
  #pragma unroll
  for (int t = 0; t < 2; ++t)
    #pragma unroll
    for (int r = 0; r < 4; ++r)
      qsh[w][quad * 4 + r][t * 16 + lc] = f2bf(qacc[t][r]);
  Frag aq;
  aq.u4 = *reinterpret_cast<const uint4*>(&qsh[w][lc][quad * 8]);

  __syncthreads();

  // S = q k^T : 14 n-tiles of 16 keys
  f32x4 s[14];
  #pragma unroll
  for (int nt = 0; nt < 14; ++nt) {
    Frag bk;
    bk.u4 = *reinterpret_cast<const uint4*>(&ksh[nt * 16 + lc][quad * 8]);
    f32x4 z = {0.f, 0.f, 0.f, 0.f};
    s[nt] = __builtin_amdgcn_mfma_f32_16x16x32_bf16(aq.b8, bk.b8, z, 0, 0, 0);
  }

  const float scale = 0.17677669529663687f;  // 1/sqrt(32)
  float mrow[4] = {-1e30f, -1e30f, -1e30f, -1e30f};
  const int qi = w * 16 + quad * 4;  // C-layout row = quad*4 + r
  #pragma unroll
  for (int nt = 0; nt < 14; ++nt) {
    int col = nt * 16 + lc;
    #pragma unroll
    for (int r = 0; r < 4; ++r) {
      float val = -1e30f;
      if (col < NPOS)
        val = s[nt][r] * scale + pbias[(size_t)(h * 64 + qi + r) * NPOS + col];
      s[nt][r] = val;
      mrow[r] = fmaxf(mrow[r], val);
    }
  }
  #pragma unroll
  for (int m = 1; m < 16; m <<= 1) {
    #pragma unroll
    for (int r = 0; r < 4; ++r) mrow[r] = fmaxf(mrow[r], __shfl_xor(mrow[r], m));
  }
  float lsum[4] = {0.f, 0.f, 0.f, 0.f};
  #pragma unroll
  for (int nt = 0; nt < 14; ++nt) {
    #pragma unroll
    for (int r = 0; r < 4; ++r) {
      float p = __expf(s[nt][r] - mrow[r]);
      s[nt][r] = p;
      lsum[r] += p;
    }
  }
  #pragma unroll
  for (int m = 1; m < 16; m <<= 1) {
    #pragma unroll
    for (int r = 0; r < 4; ++r) lsum[r] += __shfl_xor(lsum[r], m);
  }
  // P -> LDS (C-layout to A-layout round trip), per-wave private region
  #pragma unroll
  for (int nt = 0; nt < 14; ++nt) {
    #pragma unroll
    for (int r = 0; r < 4; ++r) psh[w][quad * 4 + r][nt * 16 + lc] = f2bf(s[nt][r]);
  }

  // O = P V : K = 224 in 7 steps of 32
  f32x4 o[2] = {};
  #pragma unroll
  for (int kt = 0; kt < 7; ++kt) {
    Frag ap;
    ap.u4 = *reinterpret_cast<const uint4*>(&psh[w][lc][kt * 32 + quad * 8]);
    #pragma unroll
    for (int t = 0; t < 2; ++t) {
      Frag bv;
      bv.u4 = *reinterpret_cast<const uint4*>(&vth[t * 16 + lc][kt * 32 + quad * 8]);
      o[t] = __builtin_amdgcn_mfma_f32_16x16x32_bf16(ap.b8, bv.b8, o[t], 0, 0, 0);
    }
  }
  #pragma unroll
  for (int t = 0; t < 2; ++t) {
    #pragma unroll
    for (int r = 0; r < 4; ++r)
      osh[w * 16 + quad * 4 + r][t * 16 + lc] = o[t][r] / lsum[r];
  }
  __syncthreads();

  // write: out[b][h*32+d][by*8+yy][bx*8 .. +8], f32, two float4 per lane
  {
    int d = tid >> 3, yy = tid & 7;
    float4 o0, o1;
    o0.x = osh[yy * 8 + 0][d]; o0.y = osh[yy * 8 + 1][d];
    o0.z = osh[yy * 8 + 2][d]; o0.w = osh[yy * 8 + 3][d];
    o1.x = osh[yy * 8 + 4][d]; o1.y = osh[yy * 8 + 5][d];
    o1.z = osh[yy * 8 + 6][d]; o1.w = osh[yy * 8 + 7][d];
    float* op = out + ((size_t)(b * NC + h * 32 + d) * NH + by * 8 + yy) * NW + bx * 8;
    *reinterpret_cast<float4*>(op) = o0;
    *reinterpret_cast<float4*>(op + 4) = o1;
  }
}

// ---------------------------------------------------------------------------
extern "C" void kernel_launch(void* const* d_in, const int* in_sizes, int n_in,
                              void* d_out, int out_size, void* d_ws, size_t ws_size,
                              hipStream_t stream) {
  const float* x   = (const float*)d_in[0];  // (16,256,64,64) f32
  const float* wq  = (const float*)d_in[1];  // (256,256) f32
  const float* wkv = (const float*)d_in[2];  // (512,256) f32
  const float* pb  = (const float*)d_in[3];  // (8,64,196) f32
  float* outp = (float*)d_out;               // (16,256,64,64) f32

  // workspace: kv bf16 = 16*4096*512*2 B = 64 MiB
  ushort* kvb = (ushort*)d_ws;

  k_kv<<<dim3(NH, NKV / 128, NB), 256, 0, stream>>>(x, wkv, kvb);
  k_attn<<<dim3(64, HEADS, NB), 256, 0, stream>>>(x, wq, kvb, pb, outp);
}

// Round 4
// 379.386 us; speedup vs baseline: 1.2181x; 1.2181x over previous
//
#include <hip/hip_runtime.h>
#include <hip/hip_bf16.h>
#include <stdint.h>

// Problem constants (B,C,H,W)=(16,256,64,64), HEADS=8, BS=8, HALO=3
// Inputs f32; MFMA math bf16, f32 accumulate; output f32.
#define HEADS 8
#define WIN 14
#define NPOS 196          // WIN*WIN
#define NPAD 224          // padded key count = 7*32
#define NB 16
#define NC 256
#define NH 64
#define NW 64
#define NP 4096           // NH*NW
#define NKV 512           // kv channels (fallback layout)
#define NOC 768           // q(256) + kv(512) channels (fast layout)

typedef __bf16 bf16_t;
typedef bf16_t bf16x8 __attribute__((ext_vector_type(8)));
typedef float f32x4 __attribute__((ext_vector_type(4)));

union Frag {
  uint4 u4;
  bf16x8 b8;
  ushort us[8];
};

__device__ __forceinline__ ushort f2bf(float f) {
  bf16_t h = (bf16_t)f;
  return __builtin_bit_cast(ushort, h);
}
__device__ __forceinline__ bf16x8 load_bf8(const float* __restrict__ p) {
  float4 a = *reinterpret_cast<const float4*>(p);
  float4 b = *reinterpret_cast<const float4*>(p + 4);
  bf16x8 r;
  r[0] = (bf16_t)a.x; r[1] = (bf16_t)a.y; r[2] = (bf16_t)a.z; r[3] = (bf16_t)a.w;
  r[4] = (bf16_t)b.x; r[5] = (bf16_t)b.y; r[6] = (bf16_t)b.z; r[7] = (bf16_t)b.w;
  return r;
}

// ===========================================================================
// FAST PATH (ws >= 96 MiB): k_proj -> qkv[b][p][768], then k_attn_f
// ===========================================================================

// ---------------------------------------------------------------------------
// k_proj: qkv[b][p][oc] = sum_c x[b][c][p] * Wall[oc][c], Wall=[Wq;Wkv].
// wg = 64 p (one image row) x 256 oc, 4 waves (2m x 2n of 32p x 128oc).
// LDS 33.8 KB -> 4 wg/CU. XOR-swizzled A staging; LDS-transposed epilogue
// for coalesced uint4 stores.
// ---------------------------------------------------------------------------
__global__ __launch_bounds__(256) void k_proj(const float* __restrict__ x,
                                              const float* __restrict__ wq,
                                              const float* __restrict__ wkv,
                                              ushort* __restrict__ qkv) {
  __shared__ __align__(16) ushort As[64][264];
  const int b = blockIdx.z, y = blockIdx.x;
  const int n0 = blockIdx.y * 256;
  const int tid = threadIdx.x, lane = tid & 63, wid = tid >> 6;
  const int quad = lane >> 4, lc = lane & 15;
  // stage As[px][c ^ swz(px)] = bf16(x[b][c][y][px]); swz = ((px>>2)&3)<<3
  #pragma unroll
  for (int it = 0; it < 16; ++it) {
    int i = it * 256 + tid;
    int c = i >> 4, xs = (i & 15) * 4;
    float4 v = *reinterpret_cast<const float4*>(x + ((size_t)(b * NC + c)) * NP + y * NW + xs);
    #pragma unroll
    for (int j = 0; j < 4; ++j) {
      int row = xs + j;
      float f = (j == 0) ? v.x : (j == 1) ? v.y : (j == 2) ? v.z : v.w;
      As[row][c ^ ((((row >> 2) & 3)) << 3)] = f2bf(f);
    }
  }
  __syncthreads();
  const int wm = (wid & 1) * 32, wn = (wid >> 1) * 128;
  const int swz = ((lc >> 2) & 3) << 3;   // row swizzle for fragment rows wm+*+lc
  f32x4 acc[2][8] = {};
  #pragma unroll
  for (int ks = 0; ks < 8; ++ks) {
    const int k0 = ks * 32 + quad * 8;
    Frag a0, a1;
    a0.u4 = *reinterpret_cast<const uint4*>(&As[wm + lc][k0 ^ swz]);
    a1.u4 = *reinterpret_cast<const uint4*>(&As[wm + 16 + lc][k0 ^ swz]);
    #pragma unroll
    for (int nh = 0; nh < 2; ++nh) {
      bf16x8 bb[4];
      #pragma unroll
      for (int nt = 0; nt < 4; ++nt) {
        int oc = n0 + wn + nh * 64 + nt * 16 + lc;
        const float* wp = (oc < 256) ? (wq + (size_t)oc * NC) : (wkv + (size_t)(oc - 256) * NC);
        bb[nt] = load_bf8(wp + k0);
      }
      #pragma unroll
      for (int nt = 0; nt < 4; ++nt) {
        acc[0][nh * 4 + nt] = __builtin_amdgcn_mfma_f32_16x16x32_bf16(a0.b8, bb[nt], acc[0][nh * 4 + nt], 0, 0, 0);
        acc[1][nh * 4 + nt] = __builtin_amdgcn_mfma_f32_16x16x32_bf16(a1.b8, bb[nt], acc[1][nh * 4 + nt], 0, 0, 0);
      }
    }
  }
  __syncthreads();
  // epilogue: acc -> As as [p][oc_local] bf16 (unswizzled; fresh epoch)
  #pragma unroll
  for (int mt = 0; mt < 2; ++mt)
    #pragma unroll
    for (int nn = 0; nn < 8; ++nn)
      #pragma unroll
      for (int r = 0; r < 4; ++r)
        As[wm + mt * 16 + quad * 4 + r][wn + nn * 16 + lc] = f2bf(acc[mt][nn][r]);
  __syncthreads();
  // coalesced store: 2048 uint4 over 256 threads
  #pragma unroll
  for (int v8 = 0; v8 < 8; ++v8) {
    int flat = v8 * 256 + tid;
    int p = flat >> 5, seg = flat & 31;
    uint4 u = *reinterpret_cast<const uint4*>(&As[p][seg * 8]);
    *reinterpret_cast<uint4*>(qkv + ((size_t)(b * NP) + y * NW + p) * NOC + n0 + seg * 8) = u;
  }
}

// ---------------------------------------------------------------------------
// k_attn_f: one wg per (b, block, head); 4 waves x 16 queries. LDS 45.3 KB
// -> 3 wg/CU. No softmax max-pass (scores bounded, f32-exp safe). PV uses
// slab-interleaved P round-trip (4 KB psh). v^T staging XOR-swizzled.
// ---------------------------------------------------------------------------
__global__ __launch_bounds__(256) void k_attn_f(const ushort* __restrict__ qkv,
                                                const float* __restrict__ pbias,
                                                float* __restrict__ out) {
  __shared__ __align__(16) ushort ksh[NPAD][40];    // [key][d]
  __shared__ __align__(16) ushort vth[32][232];     // [d][key^swz]
  __shared__ __align__(16) ushort psh[4][16][32];   // per-wave P slab
  __shared__ __align__(16) float osh[64][33];
  const int b = blockIdx.z, h = blockIdx.y, blk = blockIdx.x;
  const int by = blk >> 3, bx = blk & 7;
  const int tid = threadIdx.x, lane = tid & 63, w = tid >> 6;
  const int quad = lane >> 4, lc = lane & 15;

  // q A-fragment straight from qkv: A[m=lc][k=quad*8+j]
  Frag aq;
  {
    int q = w * 16 + lc;
    int py = by * 8 + (q >> 3), px = bx * 8 + (q & 7);
    aq.u4 = *reinterpret_cast<const uint4*>(
        qkv + ((size_t)(b * NP + py * NW + px)) * NOC + h * 32 + quad * 8);
  }

  // stage KV window: 224 pos x 8 segs; segs 0..3 -> k, 4..7 -> v^T (swizzled)
  for (int it = 0; it < 7; ++it) {
    int i = it * 256 + tid;
    int pos = i >> 3, seg = i & 7;
    Frag v;
    v.u4 = make_uint4(0u, 0u, 0u, 0u);
    if (pos < NPOS) {
      int wy = pos / WIN;
      int wx = pos - wy * WIN;
      int yq = by * 8 - 3 + wy, xx = bx * 8 - 3 + wx;
      if ((unsigned)yq < (unsigned)NH && (unsigned)xx < (unsigned)NW)
        v.u4 = *reinterpret_cast<const uint4*>(
            qkv + ((size_t)(b * NP + yq * NW + xx)) * NOC + 256 + h * 64 + seg * 8);
    }
    if (seg < 4) {
      *reinterpret_cast<uint4*>(&ksh[pos][seg * 8]) = v.u4;
    } else {
      int d0 = (seg - 4) * 8;
      int cp = pos ^ ((seg - 4) << 3);   // XOR swizzle on key index
      #pragma unroll
      for (int j = 0; j < 8; ++j) vth[d0 + j][cp] = v.us[j];
    }
  }
  __syncthreads();

  // S = q k^T : 14 n-tiles of 16 keys
  f32x4 s[14];
  #pragma unroll
  for (int nt = 0; nt < 14; ++nt) {
    Frag bk;
    bk.u4 = *reinterpret_cast<const uint4*>(&ksh[nt * 16 + lc][quad * 8]);
    f32x4 z = {0.f, 0.f, 0.f, 0.f};
    s[nt] = __builtin_amdgcn_mfma_f32_16x16x32_bf16(aq.b8, bk.b8, z, 0, 0, 0);
  }

  const float scale = 0.17677669529663687f;  // 1/sqrt(32)
  const int qi = w * 16 + quad * 4;          // C-layout row = quad*4 + r
  float lsum[4] = {0.f, 0.f, 0.f, 0.f};
  #pragma unroll
  for (int nt = 0; nt < 14; ++nt) {
    int col = nt * 16 + lc;
    #pragma unroll
    for (int r = 0; r < 4; ++r) {
      float p = 0.f;
      if (col < NPOS)
        p = __expf(s[nt][r] * scale + pbias[(size_t)(h * 64 + qi + r) * NPOS + col]);
      s[nt][r] = p;
      lsum[r] += p;
    }
  }

  // O = P V : 7 slabs of 32 keys, P round-tripped per slab (wave-private)
  f32x4 o[2] = {};
  #pragma unroll
  for (int kt = 0; kt < 7; ++kt) {
    #pragma unroll
    for (int t = 0; t < 2; ++t)
      #pragma unroll
      for (int r = 0; r < 4; ++r)
        psh[w][quad * 4 + r][t * 16 + lc] = f2bf(s[2 * kt + t][r]);
    Frag ap;
    ap.u4 = *reinterpret_cast<const uint4*>(&psh[w][lc][quad * 8]);
    #pragma unroll
    for (int t = 0; t < 2; ++t) {
      int d = t * 16 + lc;
      int g = (kt * 4 + quad) ^ ((d >> 3) & 3);
      Frag bv;
      bv.u4 = *reinterpret_cast<const uint4*>(&vth[d][g * 8]);
      o[t] = __builtin_amdgcn_mfma_f32_16x16x32_bf16(ap.b8, bv.b8, o[t], 0, 0, 0);
    }
  }

  #pragma unroll
  for (int m = 1; m < 16; m <<= 1)
    #pragma unroll
    for (int r = 0; r < 4; ++r) lsum[r] += __shfl_xor(lsum[r], m);
  float rinv[4];
  #pragma unroll
  for (int r = 0; r < 4; ++r) rinv[r] = 1.0f / lsum[r];
  #pragma unroll
  for (int t = 0; t < 2; ++t)
    #pragma unroll
    for (int r = 0; r < 4; ++r)
      osh[w * 16 + quad * 4 + r][t * 16 + lc] = o[t][r] * rinv[r];
  __syncthreads();

  // write: out[b][h*32+d][by*8+yy][bx*8..+8], f32, two float4 per lane
  {
    int d = tid >> 3, yy = tid & 7;
    float4 o0, o1;
    o0.x = osh[yy * 8 + 0][d]; o0.y = osh[yy * 8 + 1][d];
    o0.z = osh[yy * 8 + 2][d]; o0.w = osh[yy * 8 + 3][d];
    o1.x = osh[yy * 8 + 4][d]; o1.y = osh[yy * 8 + 5][d];
    o1.z = osh[yy * 8 + 6][d]; o1.w = osh[yy * 8 + 7][d];
    float* op = out + ((size_t)(b * NC + h * 32 + d) * NH + by * 8 + yy) * NW + bx * 8;
    *reinterpret_cast<float4*>(op) = o0;
    *reinterpret_cast<float4*>(op + 4) = o1;
  }
}

// ===========================================================================
// FALLBACK PATH (ws < 96 MiB): Round-3 kernels, proven correct
// ===========================================================================
__global__ __launch_bounds__(256) void k_kv(const float* __restrict__ x,
                                            const float* __restrict__ wkv,
                                            ushort* __restrict__ kvb) {
  __shared__ __align__(16) ushort As[64][264];
  const int b = blockIdx.z;
  const int y = blockIdx.x;
  const int n0 = blockIdx.y * 128;
  const int tid = threadIdx.x;
  const int lane = tid & 63, wid = tid >> 6;
  const int quad = lane >> 4, lc = lane & 15;
  #pragma unroll
  for (int it = 0; it < 16; ++it) {
    int i = it * 256 + tid;
    int c = i >> 4, xs = (i & 15) * 4;
    float4 v = *reinterpret_cast<const float4*>(x + ((size_t)(b * NC + c)) * NP + y * NW + xs);
    As[xs + 0][c] = f2bf(v.x);
    As[xs + 1][c] = f2bf(v.y);
    As[xs + 2][c] = f2bf(v.z);
    As[xs + 3][c] = f2bf(v.w);
  }
  __syncthreads();
  const int wm = (wid & 1) * 32, wn = (wid >> 1) * 64;
  f32x4 acc[2][4] = {};
  #pragma unroll
  for (int ks = 0; ks < 8; ++ks) {
    const int k0 = ks * 32 + quad * 8;
    Frag a[2];
    bf16x8 bb[4];
    #pragma unroll
    for (int mt = 0; mt < 2; ++mt)
      a[mt].u4 = *reinterpret_cast<const uint4*>(&As[wm + mt * 16 + lc][k0]);
    #pragma unroll
    for (int nt = 0; nt < 4; ++nt) {
      int oc = n0 + wn + nt * 16 + lc;
      bb[nt] = load_bf8(wkv + (size_t)oc * NC + k0);
    }
    #pragma unroll
    for (int mt = 0; mt < 2; ++mt)
      #pragma unroll
      for (int nt = 0; nt < 4; ++nt)
        acc[mt][nt] = __builtin_amdgcn_mfma_f32_16x16x32_bf16(a[mt].b8, bb[nt], acc[mt][nt], 0, 0, 0);
  }
  #pragma unroll
  for (int mt = 0; mt < 2; ++mt) {
    #pragma unroll
    for (int r = 0; r < 4; ++r) {
      int pl = wm + mt * 16 + quad * 4 + r;
      #pragma unroll
      for (int nt = 0; nt < 4; ++nt) {
        int oc = n0 + wn + nt * 16 + lc;
        kvb[((size_t)(b * NP + y * NW + pl)) * NKV + oc] = f2bf(acc[mt][nt][r]);
      }
    }
  }
}

__global__ __launch_bounds__(256) void k_attn_v3(const float* __restrict__ x,
                                                 const float* __restrict__ wq,
                                                 const ushort* __restrict__ kvb,
                                                 const float* __restrict__ pbias,
                                                 float* __restrict__ out) {
  __shared__ __align__(16) ushort ksh[NPAD][40];
  __shared__ __align__(16) ushort vth[32][232];
  __shared__ __align__(16) ushort psh[4][16][232];
  __shared__ __align__(16) ushort qsh[4][16][32];
  __shared__ __align__(16) float osh[64][33];
  const int b = blockIdx.z, h = blockIdx.y, blk = blockIdx.x;
  const int by = blk >> 3, bx = blk & 7;
  const int tid = threadIdx.x, lane = tid & 63, w = tid >> 6;
  const int quad = lane >> 4, lc = lane & 15;

  for (int it = 0; it < 7; ++it) {
    int i = it * 256 + tid;
    int pos = i >> 3, seg = i & 7;
    Frag v;
    v.u4 = make_uint4(0u, 0u, 0u, 0u);
    if (pos < NPOS) {
      int wy = pos / WIN;
      int wx = pos - wy * WIN;
      int yq = by * 8 - 3 + wy, xx = bx * 8 - 3 + wx;
      if ((unsigned)yq < (unsigned)NH && (unsigned)xx < (unsigned)NW)
        v.u4 = *reinterpret_cast<const uint4*>(
            kvb + ((size_t)(b * NP + yq * NW + xx)) * NKV + h * 64 + seg * 8);
    }
    if (seg < 4) {
      *reinterpret_cast<uint4*>(&ksh[pos][seg * 8]) = v.u4;
    } else {
      int d0 = (seg - 4) * 8;
      #pragma unroll
      for (int j = 0; j < 8; ++j) vth[d0 + j][pos] = v.us[j];
    }
  }

  f32x4 qacc[2] = {};
  {
    const int q = w * 16 + lc;
    const size_t p = (size_t)(by * 8 + (q >> 3)) * NW + bx * 8 + (q & 7);
    #pragma unroll
    for (int ks = 0; ks < 8; ++ks) {
      const int k0 = ks * 32 + quad * 8;
      Frag ax;
      #pragma unroll
      for (int j = 0; j < 8; ++j)
        ax.us[j] = f2bf(x[((size_t)(b * NC + k0 + j)) * NP + p]);
      bf16x8 bw0 = load_bf8(wq + (size_t)(h * 32 + lc) * NC + k0);
      bf16x8 bw1 = load_bf8(wq + (size_t)(h * 32 + 16 + lc) * NC + k0);
      qacc[0] = __builtin_amdgcn_mfma_f32_16x16x32_bf16(ax.b8, bw0, qacc[0], 0, 0, 0);
      qacc[1] = __builtin_amdgcn_mfma_f32_16x16x32_bf16(ax.b8, bw1, qacc[1], 0, 0, 0);
    }
  }
  #pragma unroll
  for (int t = 0; t < 2; ++t)
    #pragma unroll
    for (int r = 0; r < 4; ++r)
      qsh[w][quad * 4 + r][t * 16 + lc] = f2bf(qacc[t][r]);
  Frag aq;
  aq.u4 = *reinterpret_cast<const uint4*>(&qsh[w][lc][quad * 8]);

  __syncthreads();

  f32x4 s[14];
  #pragma unroll
  for (int nt = 0; nt < 14; ++nt) {
    Frag bk;
    bk.u4 = *reinterpret_cast<const uint4*>(&ksh[nt * 16 + lc][quad * 8]);
    f32x4 z = {0.f, 0.f, 0.f, 0.f};
    s[nt] = __builtin_amdgcn_mfma_f32_16x16x32_bf16(aq.b8, bk.b8, z, 0, 0, 0);
  }

  const float scale = 0.17677669529663687f;
  const int qi = w * 16 + quad * 4;
  float lsum[4] = {0.f, 0.f, 0.f, 0.f};
  #pragma unroll
  for (int nt = 0; nt < 14; ++nt) {
    int col = nt * 16 + lc;
    #pragma unroll
    for (int r = 0; r < 4; ++r) {
      float p = 0.f;
      if (col < NPOS)
        p = __expf(s[nt][r] * scale + pbias[(size_t)(h * 64 + qi + r) * NPOS + col]);
      s[nt][r] = p;
      lsum[r] += p;
    }
  }
  #pragma unroll
  for (int m = 1; m < 16; m <<= 1) {
    #pragma unroll
    for (int r = 0; r < 4; ++r) lsum[r] += __shfl_xor(lsum[r], m);
  }
  #pragma unroll
  for (int nt = 0; nt < 14; ++nt) {
    #pragma unroll
    for (int r = 0; r < 4; ++r) psh[w][quad * 4 + r][nt * 16 + lc] = f2bf(s[nt][r]);
  }
  f32x4 o[2] = {};
  #pragma unroll
  for (int kt = 0; kt < 7; ++kt) {
    Frag ap;
    ap.u4 = *reinterpret_cast<const uint4*>(&psh[w][lc][kt * 32 + quad * 8]);
    #pragma unroll
    for (int t = 0; t < 2; ++t) {
      Frag bv;
      bv.u4 = *reinterpret_cast<const uint4*>(&vth[t * 16 + lc][kt * 32 + quad * 8]);
      o[t] = __builtin_amdgcn_mfma_f32_16x16x32_bf16(ap.b8, bv.b8, o[t], 0, 0, 0);
    }
  }
  #pragma unroll
  for (int t = 0; t < 2; ++t)
    #pragma unroll
    for (int r = 0; r < 4; ++r)
      osh[w * 16 + quad * 4 + r][t * 16 + lc] = o[t][r] / lsum[r];
  __syncthreads();
  {
    int d = tid >> 3, yy = tid & 7;
    float4 o0, o1;
    o0.x = osh[yy * 8 + 0][d]; o0.y = osh[yy * 8 + 1][d];
    o0.z = osh[yy * 8 + 2][d]; o0.w = osh[yy * 8 + 3][d];
    o1.x = osh[yy * 8 + 4][d]; o1.y = osh[yy * 8 + 5][d];
    o1.z = osh[yy * 8 + 6][d]; o1.w = osh[yy * 8 + 7][d];
    float* op = out + ((size_t)(b * NC + h * 32 + d) * NH + by * 8 + yy) * NW + bx * 8;
    *reinterpret_cast<float4*>(op) = o0;
    *reinterpret_cast<float4*>(op + 4) = o1;
  }
}

// ---------------------------------------------------------------------------
extern "C" void kernel_launch(void* const* d_in, const int* in_sizes, int n_in,
                              void* d_out, int out_size, void* d_ws, size_t ws_size,
                              hipStream_t stream) {
  const float* x   = (const float*)d_in[0];  // (16,256,64,64) f32
  const float* wq  = (const float*)d_in[1];  // (256,256) f32
  const float* wkv = (const float*)d_in[2];  // (512,256) f32
  const float* pb  = (const float*)d_in[3];  // (8,64,196) f32
  float* outp = (float*)d_out;               // (16,256,64,64) f32

  const size_t need_fast = (size_t)NB * NP * NOC * sizeof(ushort);  // 96 MiB
  if (ws_size >= need_fast) {
    ushort* qkv = (ushort*)d_ws;
    k_proj<<<dim3(NH, 3, NB), 256, 0, stream>>>(x, wq, wkv, qkv);
    k_attn_f<<<dim3(64, HEADS, NB), 256, 0, stream>>>(qkv, pb, outp);
  } else {
    ushort* kvb = (ushort*)d_ws;               // 64 MiB
    k_kv<<<dim3(NH, NKV / 128, NB), 256, 0, stream>>>(x, wkv, kvb);
    k_attn_v3<<<dim3(64, HEADS, NB), 256, 0, stream>>>(x, wq, kvb, pb, outp);
  }
}

// Round 5
// 291.645 us; speedup vs baseline: 1.5845x; 1.3008x over previous
//
#include <hip/hip_runtime.h>
#include <hip/hip_bf16.h>
#include <stdint.h>

// Problem constants (B,C,H,W)=(16,256,64,64), HEADS=8, BS=8, HALO=3
// Inputs f32; MFMA math bf16, f32 accumulate; output f32.
#define HEADS 8
#define WIN 14
#define NPOS 196          // WIN*WIN
#define NPAD 224          // padded key count = 7*32
#define NB 16
#define NC 256
#define NH 64
#define NW 64
#define NP 4096           // NH*NW
#define NKV 512           // kv channels (fallback layout)
#define NOC 768           // q(256) + kv(512) channels

typedef __bf16 bf16_t;
typedef bf16_t bf16x8 __attribute__((ext_vector_type(8)));
typedef float f32x4 __attribute__((ext_vector_type(4)));

union Frag {
  uint4 u4;
  bf16x8 b8;
  ushort us[8];
};

__device__ __forceinline__ ushort f2bf(float f) {
  bf16_t h = (bf16_t)f;
  return __builtin_bit_cast(ushort, h);
}
__device__ __forceinline__ bf16x8 load_bf8(const float* __restrict__ p) {
  float4 a = *reinterpret_cast<const float4*>(p);
  float4 b = *reinterpret_cast<const float4*>(p + 4);
  bf16x8 r;
  r[0] = (bf16_t)a.x; r[1] = (bf16_t)a.y; r[2] = (bf16_t)a.z; r[3] = (bf16_t)a.w;
  r[4] = (bf16_t)b.x; r[5] = (bf16_t)b.y; r[6] = (bf16_t)b.z; r[7] = (bf16_t)b.w;
  return r;
}

// bf16 weights, converted once per launch (same data every call)
__device__ ushort g_wb[NOC * NC];

// ===========================================================================
// k_wcast: [Wq;Wkv] f32 -> g_wb bf16. 96 wg x 256 thr x 8 elem.
// ===========================================================================
__global__ __launch_bounds__(256) void k_wcast(const float* __restrict__ wq,
                                               const float* __restrict__ wkv) {
  int idx = (blockIdx.x * 256 + threadIdx.x) * 8;
  int oc = idx >> 8, c = idx & 255;
  const float* src = (oc < 256) ? (wq + (size_t)oc * NC + c)
                                : (wkv + (size_t)(oc - 256) * NC + c);
  Frag v;
  v.b8 = load_bf8(src);
  *reinterpret_cast<uint4*>(g_wb + idx) = v.u4;
}

// ===========================================================================
// k_xt: x[b][c][p] f32 -> xt[b*NP+p][c] bf16. 64p x 64c tiles via LDS.
// ===========================================================================
__global__ __launch_bounds__(256) void k_xt(const float* __restrict__ x,
                                            ushort* __restrict__ xt) {
  __shared__ __align__(16) ushort ls[64][66];
  const int b = blockIdx.z, p0 = blockIdx.x * 64, c0 = blockIdx.y * 64;
  const int tid = threadIdx.x;
  #pragma unroll
  for (int it = 0; it < 4; ++it) {
    int i = it * 256 + tid;
    int c = i >> 4, ps = (i & 15) * 4;
    float4 v = *reinterpret_cast<const float4*>(x + ((size_t)(b * NC + c0 + c)) * NP + p0 + ps);
    ls[ps + 0][c] = f2bf(v.x);
    ls[ps + 1][c] = f2bf(v.y);
    ls[ps + 2][c] = f2bf(v.z);
    ls[ps + 3][c] = f2bf(v.w);
  }
  __syncthreads();
  #pragma unroll
  for (int it = 0; it < 2; ++it) {
    int i = it * 256 + tid;
    int p = i >> 3, cs = (i & 7) * 8;
    Frag o;
    #pragma unroll
    for (int j = 0; j < 8; ++j) o.us[j] = ls[p][cs + j];
    *reinterpret_cast<uint4*>(xt + ((size_t)(b * NP) + p0 + p) * NC + c0 + cs) = o.u4;
  }
}

// ===========================================================================
// k_proj2: qkv[row][oc] = sum_c xt[row][c] * wb[oc][c]. M=65536 rows.
// Tile 128 rows x 256 oc; 4 waves 2x2 (64 rows x 128 oc each, acc 4x8).
// ===========================================================================
__global__ __launch_bounds__(256, 2) void k_proj2(const ushort* __restrict__ xt,
                                                  ushort* __restrict__ qkv) {
  __shared__ __align__(16) ushort As[128][264];
  const int row0 = blockIdx.x * 128;
  const int n0 = blockIdx.y * 256;
  const int tid = threadIdx.x, lane = tid & 63, wid = tid >> 6;
  const int quad = lane >> 4, lc = lane & 15;
  // stage 128x256 bf16 (64 KB): 16 uint4 per thread, coalesced
  #pragma unroll
  for (int it = 0; it < 16; ++it) {
    int i = it * 256 + tid;
    int r = i >> 5, cs = (i & 31) * 8;
    uint4 v = *reinterpret_cast<const uint4*>(xt + ((size_t)(row0 + r)) * NC + cs);
    *reinterpret_cast<uint4*>(&As[r][cs]) = v;
  }
  __syncthreads();
  const int wm = (wid & 1) * 64, wn = (wid >> 1) * 128;
  f32x4 acc[4][8] = {};
  #pragma unroll
  for (int ks = 0; ks < 8; ++ks) {
    const int k0 = ks * 32 + quad * 8;
    Frag a[4];
    #pragma unroll
    for (int mt = 0; mt < 4; ++mt)
      a[mt].u4 = *reinterpret_cast<const uint4*>(&As[wm + mt * 16 + lc][k0]);
    #pragma unroll
    for (int ng = 0; ng < 2; ++ng) {
      Frag bb[4];
      #pragma unroll
      for (int j = 0; j < 4; ++j) {
        int oc = n0 + wn + (ng * 4 + j) * 16 + lc;
        bb[j].u4 = *reinterpret_cast<const uint4*>(g_wb + (size_t)oc * NC + k0);
      }
      #pragma unroll
      for (int mt = 0; mt < 4; ++mt)
        #pragma unroll
        for (int j = 0; j < 4; ++j)
          acc[mt][ng * 4 + j] = __builtin_amdgcn_mfma_f32_16x16x32_bf16(
              a[mt].b8, bb[j].b8, acc[mt][ng * 4 + j], 0, 0, 0);
    }
  }
  __syncthreads();
  // epilogue: acc -> As[row][oc_local] bf16, then coalesced uint4 stores
  #pragma unroll
  for (int mt = 0; mt < 4; ++mt)
    #pragma unroll
    for (int nn = 0; nn < 8; ++nn)
      #pragma unroll
      for (int r = 0; r < 4; ++r)
        As[wm + mt * 16 + quad * 4 + r][wn + nn * 16 + lc] = f2bf(acc[mt][nn][r]);
  __syncthreads();
  #pragma unroll
  for (int it = 0; it < 16; ++it) {
    int i = it * 256 + tid;
    int r = i >> 5, cs = (i & 31) * 8;
    uint4 u = *reinterpret_cast<const uint4*>(&As[r][cs]);
    *reinterpret_cast<uint4*>(qkv + ((size_t)(row0 + r)) * NOC + n0 + cs) = u;
  }
}

// ===========================================================================
// k_attn_f2: one wg per (b, block, head); 4 waves x 16 queries.
// LDS 36 KB -> 4 wg/CU (osh overlays ksh after QK phase).
// ===========================================================================
__global__ __launch_bounds__(256) void k_attn_f2(const ushort* __restrict__ qkv,
                                                 const float* __restrict__ pbias,
                                                 float* __restrict__ out) {
  __shared__ __align__(16) ushort ksh[NPAD][40];    // 17920 B; osh overlays
  __shared__ __align__(16) ushort vth[32][232];     // [d][key^swz]
  __shared__ __align__(16) ushort psh[4][16][32];   // per-wave P slab
  float (*osh)[33] = reinterpret_cast<float(*)[33]>(&ksh[0][0]);  // 8448 B
  const int b = blockIdx.z, h = blockIdx.y, blk = blockIdx.x;
  const int by = blk >> 3, bx = blk & 7;
  const int tid = threadIdx.x, lane = tid & 63, w = tid >> 6;
  const int quad = lane >> 4, lc = lane & 15;

  // q A-fragment straight from qkv: A[m=lc][k=quad*8+j]
  Frag aq;
  {
    int q = w * 16 + lc;
    int py = by * 8 + (q >> 3), px = bx * 8 + (q & 7);
    aq.u4 = *reinterpret_cast<const uint4*>(
        qkv + ((size_t)(b * NP + py * NW + px)) * NOC + h * 32 + quad * 8);
  }

  // stage KV window: 224 pos x 8 segs; segs 0..3 -> k, 4..7 -> v^T (swizzled)
  for (int it = 0; it < 7; ++it) {
    int i = it * 256 + tid;
    int pos = i >> 3, seg = i & 7;
    Frag v;
    v.u4 = make_uint4(0u, 0u, 0u, 0u);
    if (pos < NPOS) {
      int wy = pos / WIN;
      int wx = pos - wy * WIN;
      int yq = by * 8 - 3 + wy, xx = bx * 8 - 3 + wx;
      if ((unsigned)yq < (unsigned)NH && (unsigned)xx < (unsigned)NW)
        v.u4 = *reinterpret_cast<const uint4*>(
            qkv + ((size_t)(b * NP + yq * NW + xx)) * NOC + 256 + h * 64 + seg * 8);
    }
    if (seg < 4) {
      *reinterpret_cast<uint4*>(&ksh[pos][seg * 8]) = v.u4;
    } else {
      int d0 = (seg - 4) * 8;
      int cp = pos ^ ((seg - 4) << 3);   // XOR swizzle on key index
      #pragma unroll
      for (int j = 0; j < 8; ++j) vth[d0 + j][cp] = v.us[j];
    }
  }
  __syncthreads();

  // S = q k^T : 14 n-tiles of 16 keys
  f32x4 s[14];
  #pragma unroll
  for (int nt = 0; nt < 14; ++nt) {
    Frag bk;
    bk.u4 = *reinterpret_cast<const uint4*>(&ksh[nt * 16 + lc][quad * 8]);
    f32x4 z = {0.f, 0.f, 0.f, 0.f};
    s[nt] = __builtin_amdgcn_mfma_f32_16x16x32_bf16(aq.b8, bk.b8, z, 0, 0, 0);
  }

  const float scale = 0.17677669529663687f;  // 1/sqrt(32)
  const int qi = w * 16 + quad * 4;          // C-layout row = quad*4 + r
  float lsum[4] = {0.f, 0.f, 0.f, 0.f};
  #pragma unroll
  for (int nt = 0; nt < 14; ++nt) {
    int col = nt * 16 + lc;
    #pragma unroll
    for (int r = 0; r < 4; ++r) {
      float p = 0.f;
      if (col < NPOS)
        p = __expf(s[nt][r] * scale + pbias[(size_t)(h * 64 + qi + r) * NPOS + col]);
      s[nt][r] = p;
      lsum[r] += p;
    }
  }

  // O = P V : 7 slabs of 32 keys, P round-tripped per slab (wave-private)
  f32x4 o[2] = {};
  #pragma unroll
  for (int kt = 0; kt < 7; ++kt) {
    #pragma unroll
    for (int t = 0; t < 2; ++t)
      #pragma unroll
      for (int r = 0; r < 4; ++r)
        psh[w][quad * 4 + r][t * 16 + lc] = f2bf(s[2 * kt + t][r]);
    Frag ap;
    ap.u4 = *reinterpret_cast<const uint4*>(&psh[w][lc][quad * 8]);
    #pragma unroll
    for (int t = 0; t < 2; ++t) {
      int d = t * 16 + lc;
      int g = (kt * 4 + quad) ^ ((d >> 3) & 3);
      Frag bv;
      bv.u4 = *reinterpret_cast<const uint4*>(&vth[d][g * 8]);
      o[t] = __builtin_amdgcn_mfma_f32_16x16x32_bf16(ap.b8, bv.b8, o[t], 0, 0, 0);
    }
  }

  #pragma unroll
  for (int m = 1; m < 16; m <<= 1)
    #pragma unroll
    for (int r = 0; r < 4; ++r) lsum[r] += __shfl_xor(lsum[r], m);
  float rinv[4];
  #pragma unroll
  for (int r = 0; r < 4; ++r) rinv[r] = 1.0f / lsum[r];

  __syncthreads();   // all waves done reading ksh before osh overlay write
  #pragma unroll
  for (int t = 0; t < 2; ++t)
    #pragma unroll
    for (int r = 0; r < 4; ++r)
      osh[w * 16 + quad * 4 + r][t * 16 + lc] = o[t][r] * rinv[r];
  __syncthreads();

  // write: out[b][h*32+d][by*8+yy][bx*8..+8], f32, two float4 per lane
  {
    int d = tid >> 3, yy = tid & 7;
    float4 o0, o1;
    o0.x = osh[yy * 8 + 0][d]; o0.y = osh[yy * 8 + 1][d];
    o0.z = osh[yy * 8 + 2][d]; o0.w = osh[yy * 8 + 3][d];
    o1.x = osh[yy * 8 + 4][d]; o1.y = osh[yy * 8 + 5][d];
    o1.z = osh[yy * 8 + 6][d]; o1.w = osh[yy * 8 + 7][d];
    float* op = out + ((size_t)(b * NC + h * 32 + d) * NH + by * 8 + yy) * NW + bx * 8;
    *reinterpret_cast<float4*>(op) = o0;
    *reinterpret_cast<float4*>(op + 4) = o1;
  }
}

// ===========================================================================
// MID FALLBACK (96 MiB <= ws < 128 MiB): R4 k_proj (proven) + k_attn_f2
// ===========================================================================
__global__ __launch_bounds__(256) void k_proj_r4(const float* __restrict__ x,
                                                 const float* __restrict__ wq,
                                                 const float* __restrict__ wkv,
                                                 ushort* __restrict__ qkv) {
  __shared__ __align__(16) ushort As[64][264];
  const int b = blockIdx.z, y = blockIdx.x;
  const int n0 = blockIdx.y * 256;
  const int tid = threadIdx.x, lane = tid & 63, wid = tid >> 6;
  const int quad = lane >> 4, lc = lane & 15;
  #pragma unroll
  for (int it = 0; it < 16; ++it) {
    int i = it * 256 + tid;
    int c = i >> 4, xs = (i & 15) * 4;
    float4 v = *reinterpret_cast<const float4*>(x + ((size_t)(b * NC + c)) * NP + y * NW + xs);
    #pragma unroll
    for (int j = 0; j < 4; ++j) {
      int row = xs + j;
      float f = (j == 0) ? v.x : (j == 1) ? v.y : (j == 2) ? v.z : v.w;
      As[row][c ^ ((((row >> 2) & 3)) << 3)] = f2bf(f);
    }
  }
  __syncthreads();
  const int wm = (wid & 1) * 32, wn = (wid >> 1) * 128;
  const int swz = ((lc >> 2) & 3) << 3;
  f32x4 acc[2][8] = {};
  #pragma unroll
  for (int ks = 0; ks < 8; ++ks) {
    const int k0 = ks * 32 + quad * 8;
    Frag a0, a1;
    a0.u4 = *reinterpret_cast<const uint4*>(&As[wm + lc][k0 ^ swz]);
    a1.u4 = *reinterpret_cast<const uint4*>(&As[wm + 16 + lc][k0 ^ swz]);
    #pragma unroll
    for (int nh = 0; nh < 2; ++nh) {
      bf16x8 bb[4];
      #pragma unroll
      for (int nt = 0; nt < 4; ++nt) {
        int oc = n0 + wn + nh * 64 + nt * 16 + lc;
        const float* wp = (oc < 256) ? (wq + (size_t)oc * NC) : (wkv + (size_t)(oc - 256) * NC);
        bb[nt] = load_bf8(wp + k0);
      }
      #pragma unroll
      for (int nt = 0; nt < 4; ++nt) {
        acc[0][nh * 4 + nt] = __builtin_amdgcn_mfma_f32_16x16x32_bf16(a0.b8, bb[nt], acc[0][nh * 4 + nt], 0, 0, 0);
        acc[1][nh * 4 + nt] = __builtin_amdgcn_mfma_f32_16x16x32_bf16(a1.b8, bb[nt], acc[1][nh * 4 + nt], 0, 0, 0);
      }
    }
  }
  __syncthreads();
  #pragma unroll
  for (int mt = 0; mt < 2; ++mt)
    #pragma unroll
    for (int nn = 0; nn < 8; ++nn)
      #pragma unroll
      for (int r = 0; r < 4; ++r)
        As[wm + mt * 16 + quad * 4 + r][wn + nn * 16 + lc] = f2bf(acc[mt][nn][r]);
  __syncthreads();
  #pragma unroll
  for (int v8 = 0; v8 < 8; ++v8) {
    int flat = v8 * 256 + tid;
    int p = flat >> 5, seg = flat & 31;
    uint4 u = *reinterpret_cast<const uint4*>(&As[p][seg * 8]);
    *reinterpret_cast<uint4*>(qkv + ((size_t)(b * NP) + y * NW + p) * NOC + n0 + seg * 8) = u;
  }
}

// ===========================================================================
// LOW FALLBACK (ws < 96 MiB): Round-3 kernels, proven correct
// ===========================================================================
__global__ __launch_bounds__(256) void k_kv(const float* __restrict__ x,
                                            const float* __restrict__ wkv,
                                            ushort* __restrict__ kvb) {
  __shared__ __align__(16) ushort As[64][264];
  const int b = blockIdx.z;
  const int y = blockIdx.x;
  const int n0 = blockIdx.y * 128;
  const int tid = threadIdx.x;
  const int lane = tid & 63, wid = tid >> 6;
  const int quad = lane >> 4, lc = lane & 15;
  #pragma unroll
  for (int it = 0; it < 16; ++it) {
    int i = it * 256 + tid;
    int c = i >> 4, xs = (i & 15) * 4;
    float4 v = *reinterpret_cast<const float4*>(x + ((size_t)(b * NC + c)) * NP + y * NW + xs);
    As[xs + 0][c] = f2bf(v.x);
    As[xs + 1][c] = f2bf(v.y);
    As[xs + 2][c] = f2bf(v.z);
    As[xs + 3][c] = f2bf(v.w);
  }
  __syncthreads();
  const int wm = (wid & 1) * 32, wn = (wid >> 1) * 64;
  f32x4 acc[2][4] = {};
  #pragma unroll
  for (int ks = 0; ks < 8; ++ks) {
    const int k0 = ks * 32 + quad * 8;
    Frag a[2];
    bf16x8 bb[4];
    #pragma unroll
    for (int mt = 0; mt < 2; ++mt)
      a[mt].u4 = *reinterpret_cast<const uint4*>(&As[wm + mt * 16 + lc][k0]);
    #pragma unroll
    for (int nt = 0; nt < 4; ++nt) {
      int oc = n0 + wn + nt * 16 + lc;
      bb[nt] = load_bf8(wkv + (size_t)oc * NC + k0);
    }
    #pragma unroll
    for (int mt = 0; mt < 2; ++mt)
      #pragma unroll
      for (int nt = 0; nt < 4; ++nt)
        acc[mt][nt] = __builtin_amdgcn_mfma_f32_16x16x32_bf16(a[mt].b8, bb[nt], acc[mt][nt], 0, 0, 0);
  }
  #pragma unroll
  for (int mt = 0; mt < 2; ++mt) {
    #pragma unroll
    for (int r = 0; r < 4; ++r) {
      int pl = wm + mt * 16 + quad * 4 + r;
      #pragma unroll
      for (int nt = 0; nt < 4; ++nt) {
        int oc = n0 + wn + nt * 16 + lc;
        kvb[((size_t)(b * NP + y * NW + pl)) * NKV + oc] = f2bf(acc[mt][nt][r]);
      }
    }
  }
}

__global__ __launch_bounds__(256) void k_attn_v3(const float* __restrict__ x,
                                                 const float* __restrict__ wq,
                                                 const ushort* __restrict__ kvb,
                                                 const float* __restrict__ pbias,
                                                 float* __restrict__ out) {
  __shared__ __align__(16) ushort ksh[NPAD][40];
  __shared__ __align__(16) ushort vth[32][232];
  __shared__ __align__(16) ushort psh[4][16][232];
  __shared__ __align__(16) ushort qsh[4][16][32];
  __shared__ __align__(16) float osh[64][33];
  const int b = blockIdx.z, h = blockIdx.y, blk = blockIdx.x;
  const int by = blk >> 3, bx = blk & 7;
  const int tid = threadIdx.x, lane = tid & 63, w = tid >> 6;
  const int quad = lane >> 4, lc = lane & 15;

  for (int it = 0; it < 7; ++it) {
    int i = it * 256 + tid;
    int pos = i >> 3, seg = i & 7;
    Frag v;
    v.u4 = make_uint4(0u, 0u, 0u, 0u);
    if (pos < NPOS) {
      int wy = pos / WIN;
      int wx = pos - wy * WIN;
      int yq = by * 8 - 3 + wy, xx = bx * 8 - 3 + wx;
      if ((unsigned)yq < (unsigned)NH && (unsigned)xx < (unsigned)NW)
        v.u4 = *reinterpret_cast<const uint4*>(
            kvb + ((size_t)(b * NP + yq * NW + xx)) * NKV + h * 64 + seg * 8);
    }
    if (seg < 4) {
      *reinterpret_cast<uint4*>(&ksh[pos][seg * 8]) = v.u4;
    } else {
      int d0 = (seg - 4) * 8;
      #pragma unroll
      for (int j = 0; j < 8; ++j) vth[d0 + j][pos] = v.us[j];
    }
  }

  f32x4 qacc[2] = {};
  {
    const int q = w * 16 + lc;
    const size_t p = (size_t)(by * 8 + (q >> 3)) * NW + bx * 8 + (q & 7);
    #pragma unroll
    for (int ks = 0; ks < 8; ++ks) {
      const int k0 = ks * 32 + quad * 8;
      Frag ax;
      #pragma unroll
      for (int j = 0; j < 8; ++j)
        ax.us[j] = f2bf(x[((size_t)(b * NC + k0 + j)) * NP + p]);
      bf16x8 bw0 = load_bf8(wq + (size_t)(h * 32 + lc) * NC + k0);
      bf16x8 bw1 = load_bf8(wq + (size_t)(h * 32 + 16 + lc) * NC + k0);
      qacc[0] = __builtin_amdgcn_mfma_f32_16x16x32_bf16(ax.b8, bw0, qacc[0], 0, 0, 0);
      qacc[1] = __builtin_amdgcn_mfma_f32_16x16x32_bf16(ax.b8, bw1, qacc[1], 0, 0, 0);
    }
  }
  #pragma unroll
  for (int t = 0; t < 2; ++t)
    #pragma unroll
    for (int r = 0; r < 4; ++r)
      qsh[w][quad * 4 + r][t * 16 + lc] = f2bf(qacc[t][r]);
  Frag aq;
  aq.u4 = *reinterpret_cast<const uint4*>(&qsh[w][lc][quad * 8]);

  __syncthreads();

  f32x4 s[14];
  #pragma unroll
  for (int nt = 0; nt < 14; ++nt) {
    Frag bk;
    bk.u4 = *reinterpret_cast<const uint4*>(&ksh[nt * 16 + lc][quad * 8]);
    f32x4 z = {0.f, 0.f, 0.f, 0.f};
    s[nt] = __builtin_amdgcn_mfma_f32_16x16x32_bf16(aq.b8, bk.b8, z, 0, 0, 0);
  }

  const float scale = 0.17677669529663687f;
  const int qi = w * 16 + quad * 4;
  float lsum[4] = {0.f, 0.f, 0.f, 0.f};
  #pragma unroll
  for (int nt = 0; nt < 14; ++nt) {
    int col = nt * 16 + lc;
    #pragma unroll
    for (int r = 0; r < 4; ++r) {
      float p = 0.f;
      if (col < NPOS)
        p = __expf(s[nt][r] * scale + pbias[(size_t)(h * 64 + qi + r) * NPOS + col]);
      s[nt][r] = p;
      lsum[r] += p;
    }
  }
  #pragma unroll
  for (int m = 1; m < 16; m <<= 1) {
    #pragma unroll
    for (int r = 0; r < 4; ++r) lsum[r] += __shfl_xor(lsum[r], m);
  }
  #pragma unroll
  for (int nt = 0; nt < 14; ++nt) {
    #pragma unroll
    for (int r = 0; r < 4; ++r) psh[w][quad * 4 + r][nt * 16 + lc] = f2bf(s[nt][r]);
  }
  f32x4 o[2] = {};
  #pragma unroll
  for (int kt = 0; kt < 7; ++kt) {
    Frag ap;
    ap.u4 = *reinterpret_cast<const uint4*>(&psh[w][lc][kt * 32 + quad * 8]);
    #pragma unroll
    for (int t = 0; t < 2; ++t) {
      Frag bv;
      bv.u4 = *reinterpret_cast<const uint4*>(&vth[t * 16 + lc][kt * 32 + quad * 8]);
      o[t] = __builtin_amdgcn_mfma_f32_16x16x32_bf16(ap.b8, bv.b8, o[t], 0, 0, 0);
    }
  }
  #pragma unroll
  for (int t = 0; t < 2; ++t)
    #pragma unroll
    for (int r = 0; r < 4; ++r)
      osh[w * 16 + quad * 4 + r][t * 16 + lc] = o[t][r] / lsum[r];
  __syncthreads();
  {
    int d = tid >> 3, yy = tid & 7;
    float4 o0, o1;
    o0.x = osh[yy * 8 + 0][d]; o0.y = osh[yy * 8 + 1][d];
    o0.z = osh[yy * 8 + 2][d]; o0.w = osh[yy * 8 + 3][d];
    o1.x = osh[yy * 8 + 4][d]; o1.y = osh[yy * 8 + 5][d];
    o1.z = osh[yy * 8 + 6][d]; o1.w = osh[yy * 8 + 7][d];
    float* op = out + ((size_t)(b * NC + h * 32 + d) * NH + by * 8 + yy) * NW + bx * 8;
    *reinterpret_cast<float4*>(op) = o0;
    *reinterpret_cast<float4*>(op + 4) = o1;
  }
}

// ---------------------------------------------------------------------------
extern "C" void kernel_launch(void* const* d_in, const int* in_sizes, int n_in,
                              void* d_out, int out_size, void* d_ws, size_t ws_size,
                              hipStream_t stream) {
  const float* x   = (const float*)d_in[0];  // (16,256,64,64) f32
  const float* wq  = (const float*)d_in[1];  // (256,256) f32
  const float* wkv = (const float*)d_in[2];  // (512,256) f32
  const float* pb  = (const float*)d_in[3];  // (8,64,196) f32
  float* outp = (float*)d_out;               // (16,256,64,64) f32

  const size_t qkv_bytes = (size_t)NB * NP * NOC * sizeof(ushort);  // 96 MiB
  const size_t xt_bytes  = (size_t)NB * NP * NC * sizeof(ushort);   // 32 MiB

  if (ws_size >= qkv_bytes + xt_bytes) {
    // FULL: wcast + transpose + clean bf16 GEMM + attention
    ushort* qkv = (ushort*)d_ws;
    ushort* xt  = (ushort*)((char*)d_ws + qkv_bytes);
    k_wcast<<<dim3(NOC * NC / (256 * 8)), 256, 0, stream>>>(wq, wkv);
    k_xt<<<dim3(NP / 64, NC / 64, NB), 256, 0, stream>>>(x, xt);
    k_proj2<<<dim3(NB * NP / 128, 3), 256, 0, stream>>>(xt, qkv);
    k_attn_f2<<<dim3(64, HEADS, NB), 256, 0, stream>>>(qkv, pb, outp);
  } else if (ws_size >= qkv_bytes) {
    ushort* qkv = (ushort*)d_ws;
    k_proj_r4<<<dim3(NH, 3, NB), 256, 0, stream>>>(x, wq, wkv, qkv);
    k_attn_f2<<<dim3(64, HEADS, NB), 256, 0, stream>>>(qkv, pb, outp);
  } else {
    ushort* kvb = (ushort*)d_ws;               // 64 MiB
    k_kv<<<dim3(NH, NKV / 128, NB), 256, 0, stream>>>(x, wkv, kvb);
    k_attn_v3<<<dim3(64, HEADS, NB), 256, 0, stream>>>(x, wq, kvb, pb, outp);
  }
}